// Round 3
// baseline (1919.778 us; speedup 1.0000x reference)
//
#include <hip/hip_runtime.h>
#include <hip/hip_bf16.h>

// SRPBlock forward, MFMA bf16 implicit-GEMM convs + LDS-tiled fp16 local attention.
// x=concat(old,new) [4,64,256,256] fp32 NCHW (inputs); activations flow as
// bf16 [b][pix][ch] (channel-contiguous) for MFMA; q/k as fp16 [b][pix][64];
// y-residual master in fp32.

#define HH 256
#define WW 256
#define PLANE 65536

typedef __bf16 bf16x8 __attribute__((ext_vector_type(8)));
typedef float  f32x4  __attribute__((ext_vector_type(4)));
typedef _Float16 h2 __attribute__((ext_vector_type(2)));

__device__ __forceinline__ unsigned short f2bf(float f) {
    unsigned int u = __builtin_bit_cast(unsigned int, f);
    u += 0x7fffu + ((u >> 16) & 1u);          // RNE (finite values only)
    return (unsigned short)(u >> 16);
}

__device__ __forceinline__ unsigned short f2h(float f) {
    _Float16 h = (_Float16)f;                  // v_cvt_f16_f32 (RNE)
    return __builtin_bit_cast(unsigned short, h);
}

__device__ __forceinline__ float dot2h(unsigned a, unsigned b, float c) {
#if __has_builtin(__builtin_amdgcn_fdot2)
    return __builtin_amdgcn_fdot2(__builtin_bit_cast(h2, a),
                                  __builtin_bit_cast(h2, b), c, false);
#else
    h2 av = __builtin_bit_cast(h2, a), bv = __builtin_bit_cast(h2, b);
    return fmaf((float)av.x, (float)bv.x, fmaf((float)av.y, (float)bv.y, c));
#endif
}

// ---------------- conv3x3 (pad=1, Cout=64) via MFMA 16x16x32 bf16 ----------------
// block = 256 thr = 4 waves; tile = 16x16 pixels x 64 outch.
template <int CIN, int CH, bool BIAS, bool LEAKY, bool ADDF, bool ADDX, bool MULX,
          bool OUTF, bool OUTB, bool HALF>
__global__ __launch_bounds__(256, 2) void conv_mfma(
    const unsigned short* __restrict__ in_pc,  // [b][65536][CIN] bf16
    const unsigned short* __restrict__ wb,     // [9][64][CIN] bf16
    const float* __restrict__ bias,
    const float* __restrict__ addf,            // fp32 NCHW addend (residual)
    const float* __restrict__ xold,            // fp32 NCHW [4,32,...]
    const float* __restrict__ xnew,
    float* __restrict__ outf,                  // fp32 NCHW
    unsigned short* __restrict__ outb)         // [b][65536][64] bf16 or fp16
{
    constexpr int PARTS = CH / 8;        // 16B units per pixel-row chunk
    constexpr int SWZ   = PARTS - 1;     // XOR swizzle mask
    constexpr int KC    = CH / 32;
    constexpr int INSZ  = (324 * CH > 256 * 64) ? 324 * CH : 256 * 64;

    __shared__ unsigned short lds_in[INSZ];
    __shared__ unsigned short lds_w[2][64 * CH];

    const int tid = threadIdx.x;
    const int w   = tid >> 6;
    const int ln  = tid & 63;
    const int m   = ln & 15;    // outch-in-group for A; pixel-col for B/D
    const int q   = ln >> 4;    // quad
    const int b   = blockIdx.z;
    const int tx0 = blockIdx.x * 16, ty0 = blockIdx.y * 16;
    const size_t pixb = (size_t)b * PLANE;

    f32x4 acc[4][4];
#pragma unroll
    for (int g = 0; g < 4; ++g)
#pragma unroll
        for (int p = 0; p < 4; ++p) acc[g][p] = (f32x4)0.f;

    for (int c2 = 0; c2 < CIN / CH; ++c2) {
        // ---- stage halo chunk: 324 px x CH ch ----
        for (int u = tid; u < 324 * PARTS; u += 256) {
            int pix  = u / PARTS;
            int part = u - pix * PARTS;
            int hy = pix / 18, hx = pix - hy * 18;
            int gy = ty0 + hy - 1, gx = tx0 + hx - 1;
            uint4 val = make_uint4(0u, 0u, 0u, 0u);
            if ((unsigned)gy < 256u && (unsigned)gx < 256u)
                val = *reinterpret_cast<const uint4*>(
                    in_pc + ((pixb + (size_t)gy * 256 + gx) * CIN + c2 * CH + part * 8));
            int pp = part ^ (pix & SWZ);
            *reinterpret_cast<uint4*>(&lds_in[pix * CH + pp * 8]) = val;
        }
        // ---- stage weights tap 0 ----
        for (int u = tid; u < 64 * PARTS; u += 256) {
            int oc = u / PARTS, part = u - oc * PARTS;
            uint4 val = *reinterpret_cast<const uint4*>(
                wb + ((size_t)oc * CIN + c2 * CH + part * 8));
            int pp = part ^ (oc & SWZ);
            *reinterpret_cast<uint4*>(&lds_w[0][oc * CH + pp * 8]) = val;
        }
        __syncthreads();

        for (int t = 0; t < 9; ++t) {
            if (t < 8) {  // prefetch next tap's weights into other buffer
                int bsel = (t + 1) & 1;
                for (int u = tid; u < 64 * PARTS; u += 256) {
                    int oc = u / PARTS, part = u - oc * PARTS;
                    uint4 val = *reinterpret_cast<const uint4*>(
                        wb + ((size_t)((t + 1) * 64 + oc) * CIN + c2 * CH + part * 8));
                    int pp = part ^ (oc & SWZ);
                    *reinterpret_cast<uint4*>(&lds_w[bsel][oc * CH + pp * 8]) = val;
                }
            }
            const int dy = t / 3, dx = t - dy * 3;
            const unsigned short* wl = lds_w[t & 1];
#pragma unroll
            for (int kc = 0; kc < KC; ++kc) {
                bf16x8 av[4], bv[4];
#pragma unroll
                for (int g = 0; g < 4; ++g) {
                    int oc = g * 16 + m;
                    int pp = (kc * 4 + q) ^ (oc & SWZ);
                    av[g] = *reinterpret_cast<const bf16x8*>(&wl[oc * CH + pp * 8]);
                }
#pragma unroll
                for (int p = 0; p < 4; ++p) {
                    int hp = (w * 4 + p + dy) * 18 + m + dx;
                    int pp = (kc * 4 + q) ^ (hp & SWZ);
                    bv[p] = *reinterpret_cast<const bf16x8*>(&lds_in[hp * CH + pp * 8]);
                }
#pragma unroll
                for (int g = 0; g < 4; ++g)
#pragma unroll
                    for (int p = 0; p < 4; ++p)
                        acc[g][p] = __builtin_amdgcn_mfma_f32_16x16x32_bf16(
                            av[g], bv[p], acc[g][p], 0, 0, 0);
            }
            __syncthreads();
        }
    }

    // ---------------- epilogue ----------------
    const int colx = tx0 + m;
    float4 bvec[4];
    if (BIAS) {
#pragma unroll
        for (int g = 0; g < 4; ++g)
            bvec[g] = *reinterpret_cast<const float4*>(bias + g * 16 + q * 4);
    }

#pragma unroll
    for (int g = 0; g < 4; ++g) {
#pragma unroll
        for (int p = 0; p < 4; ++p) {
            const int prow = w * 4 + p;
            const int gy   = ty0 + prow;
            float vals[4];
#pragma unroll
            for (int r = 0; r < 4; ++r) {
                int oc = g * 16 + q * 4 + r;
                float v = acc[g][p][r];
                if (BIAS) v += reinterpret_cast<const float*>(&bvec[g])[r];
                if (LEAKY) v = (v >= 0.f) ? v : 0.2f * v;
                size_t nchw = ((size_t)(b * 64 + oc)) * PLANE + (size_t)gy * 256 + colx;
                if (ADDF) v += addf[nchw];
                if (ADDX) {
                    const float* xp = (g < 2) ? xold : xnew;
                    v += xp[((size_t)(b * 32 + (oc & 31))) * PLANE + (size_t)gy * 256 + colx];
                }
                if (MULX) {
                    const float* xp = (g < 2) ? xold : xnew;
                    v *= xp[((size_t)(b * 32 + (oc & 31))) * PLANE + (size_t)gy * 256 + colx];
                }
                if (OUTF) outf[nchw] = v;
                vals[r] = v;
            }
            if (OUTB) {  // stage to LDS for [pix][ch] vector store
                ushort4 pk;
                if (HALF) {
                    pk.x = f2h(vals[0]); pk.y = f2h(vals[1]);
                    pk.z = f2h(vals[2]); pk.w = f2h(vals[3]);
                } else {
                    pk.x = f2bf(vals[0]); pk.y = f2bf(vals[1]);
                    pk.z = f2bf(vals[2]); pk.w = f2bf(vals[3]);
                }
                int pix   = prow * 16 + m;
                int part8 = g * 4 + q;
                int p16   = (part8 >> 1) ^ (pix & 7);
                *reinterpret_cast<ushort4*>(&lds_in[pix * 64 + p16 * 8 + (part8 & 1) * 4]) = pk;
            }
        }
    }
    if (OUTB) {
        __syncthreads();
        for (int u = tid; u < 2048; u += 256) {
            int pix = u >> 3, p16 = u & 7;
            uint4 val = *reinterpret_cast<const uint4*>(
                &lds_in[pix * 64 + ((p16 ^ (pix & 7)) * 8)]);
            int gy = ty0 + (pix >> 4), gx = tx0 + (pix & 15);
            *reinterpret_cast<uint4*>(
                &outb[(pixb + (size_t)gy * 256 + gx) * 64 + p16 * 8]) = val;
        }
    }
}

// ---------------- local similarity (LDS-tiled, fp16 dot2) ----------------
// att[b][pix][p] = dot64(q[pix], k[pix+(di-4,dj-4)]), p=di*9+dj; ch 81..95 = 0.
// block = 256 thr = 16x16 pixel tile; k halo 24x24 staged per 32-ch chunk.
__global__ __launch_bounds__(256, 3) void local_sim(
    const unsigned short* __restrict__ qh, const unsigned short* __restrict__ kh,
    unsigned short* __restrict__ att)
{
    __shared__ unsigned short lds_k[576 * 32];   // 24*24 px x 32ch fp16 = 36.9 KB

    const int tid = threadIdx.x;
    const int tx = tid & 15, ty = tid >> 4;
    const int bx = blockIdx.x * 16, by = blockIdx.y * 16;
    const int b  = blockIdx.z;
    const size_t pixb = (size_t)b * PLANE;

    float acc[81];
#pragma unroll
    for (int p = 0; p < 81; ++p) acc[p] = 0.f;

    for (int c = 0; c < 2; ++c) {
        __syncthreads();
        // stage k halo chunk: 576 px x 32 ch (zero-filled OOB)
        for (int u = tid; u < 2304; u += 256) {
            int pix = u >> 2, part = u & 3;
            int hy = pix / 24, hx = pix - hy * 24;
            int gy = by + hy - 4, gx = bx + hx - 4;
            uint4 val = make_uint4(0u, 0u, 0u, 0u);
            if ((unsigned)gy < 256u && (unsigned)gx < 256u)
                val = *reinterpret_cast<const uint4*>(
                    kh + ((pixb + (size_t)gy * 256 + gx) * 64 + c * 32 + part * 8));
            int pp = part ^ (pix & 3) ^ ((pix >> 2) & 3);
            *reinterpret_cast<uint4*>(&lds_k[pix * 32 + pp * 8]) = val;
        }
        __syncthreads();

        // q chunk into registers (16 half2)
        const unsigned short* qp = qh + (pixb + (size_t)(by + ty) * 256 + bx + tx) * 64 + c * 32;
        uint4 qv[4];
#pragma unroll
        for (int j = 0; j < 4; ++j)
            qv[j] = *reinterpret_cast<const uint4*>(qp + j * 8);

#pragma unroll
        for (int di = 0; di < 9; ++di) {
#pragma unroll
            for (int dj = 0; dj < 9; ++dj) {
                const int hp = (ty + di) * 24 + tx + dj;
                float s = acc[di * 9 + dj];
#pragma unroll
                for (int part = 0; part < 4; ++part) {
                    int pp = part ^ (hp & 3) ^ ((hp >> 2) & 3);
                    uint4 kv = *reinterpret_cast<const uint4*>(&lds_k[hp * 32 + pp * 8]);
                    s = dot2h(qv[part].x, kv.x, s);
                    s = dot2h(qv[part].y, kv.y, s);
                    s = dot2h(qv[part].z, kv.z, s);
                    s = dot2h(qv[part].w, kv.w, s);
                }
                acc[di * 9 + dj] = s;
            }
        }
    }

    // pack 81 bf16 + 15 zeros -> [pix][96]
    unsigned short* op = att + (pixb + (size_t)(by + ty) * 256 + bx + tx) * 96;
#pragma unroll
    for (int g = 0; g < 10; ++g) {
        uint4 o;
        float v0 = acc[g * 8 + 0];
        float v1 = (g * 8 + 1 < 81) ? acc[g * 8 + 1] : 0.f;
        float v2 = (g * 8 + 2 < 81) ? acc[g * 8 + 2] : 0.f;
        float v3 = (g * 8 + 3 < 81) ? acc[g * 8 + 3] : 0.f;
        float v4 = (g * 8 + 4 < 81) ? acc[g * 8 + 4] : 0.f;
        float v5 = (g * 8 + 5 < 81) ? acc[g * 8 + 5] : 0.f;
        float v6 = (g * 8 + 6 < 81) ? acc[g * 8 + 6] : 0.f;
        float v7 = (g * 8 + 7 < 81) ? acc[g * 8 + 7] : 0.f;
        o.x = f2bf(v0) | ((unsigned)f2bf(v1) << 16);
        o.y = f2bf(v2) | ((unsigned)f2bf(v3) << 16);
        o.z = f2bf(v4) | ((unsigned)f2bf(v5) << 16);
        o.w = f2bf(v6) | ((unsigned)f2bf(v7) << 16);
        *reinterpret_cast<uint4*>(op + g * 8) = o;
    }
    {
        uint4 z = make_uint4(0u, 0u, 0u, 0u);
        *reinterpret_cast<uint4*>(op + 80) = make_uint4(f2bf(acc[80]), 0u, 0u, 0u);
        *reinterpret_cast<uint4*>(op + 88) = z;
    }
}

// ---------------- pack x: fp32 NCHW old/new -> bf16 [b][pix][64] ----------------
__global__ __launch_bounds__(256) void pack_x(
    const float* __restrict__ old_, const float* __restrict__ new_,
    unsigned short* __restrict__ xb)
{
    __shared__ unsigned short lds[256 * 64];
    const int tid = threadIdx.x;
    const int b = blockIdx.y;
    const size_t pixbase = (size_t)blockIdx.x * 256;
#pragma unroll
    for (int cg = 0; cg < 8; ++cg) {
        unsigned pk[4];
#pragma unroll
        for (int h = 0; h < 4; ++h) {
            int c0 = cg * 8 + h * 2;
            const float* s0 = (c0 < 32) ? old_ : new_;
            const float* s1 = ((c0 + 1) < 32) ? old_ : new_;
            float f0 = s0[((size_t)b * 32 + (c0 & 31)) * PLANE + pixbase + tid];
            float f1 = s1[((size_t)b * 32 + ((c0 + 1) & 31)) * PLANE + pixbase + tid];
            pk[h] = f2bf(f0) | ((unsigned)f2bf(f1) << 16);
        }
        int p16 = cg ^ (tid & 7);
        uint4 v; v.x = pk[0]; v.y = pk[1]; v.z = pk[2]; v.w = pk[3];
        *reinterpret_cast<uint4*>(&lds[tid * 64 + p16 * 8]) = v;
    }
    __syncthreads();
    for (int r = 0; r < 8; ++r) {
        int u = r * 256 + tid;
        int pix = u >> 3, p16 = u & 7;
        uint4 v = *reinterpret_cast<const uint4*>(&lds[pix * 64 + ((p16 ^ (pix & 7)) * 8)]);
        *reinterpret_cast<uint4*>(
            &xb[((size_t)b * PLANE + pixbase + pix) * 64 + p16 * 8]) = v;
    }
}

// ---------------- weight prep: fp32 OIHW -> bf16 [9][64][CIN] ----------------
__global__ void prep_wstd(const float* __restrict__ wq, const float* __restrict__ wk,
                          const float* __restrict__ wo1, const float* __restrict__ wo2,
                          const float* __restrict__ rw1, const float* __restrict__ rw2,
                          unsigned short* __restrict__ wstd)
{
    const int c = blockIdx.y;  // 0..19
    const float* src;
    if (c == 0) src = wq;
    else if (c == 1) src = wk;
    else if (c == 2) src = wo1;
    else if (c == 3) src = wo2;
    else if (c < 12) src = rw1 + (size_t)(c - 4) * 36864;
    else src = rw2 + (size_t)(c - 12) * 36864;
    int idx = blockIdx.x * 256 + threadIdx.x;  // 0..4095
    int o = idx >> 6, i = idx & 63;
    const float* s = src + (size_t)(o * 64 + i) * 9;
    unsigned short* d = wstd + (size_t)c * 36864 + (size_t)o * 64 + i;
#pragma unroll
    for (int t = 0; t < 9; ++t) d[(size_t)t * 4096] = f2bf(s[t]);
}

__global__ void prep_wv(const float* __restrict__ wv, unsigned short* __restrict__ wv96)
{
    int idx = blockIdx.x * 256 + threadIdx.x;  // < 6144
    int o = idx / 96, i = idx - o * 96;
    unsigned short* d = wv96 + (size_t)o * 96 + i;
    if (i < 81) {
        const float* s = wv + (size_t)(o * 81 + i) * 9;
#pragma unroll
        for (int t = 0; t < 9; ++t) d[(size_t)t * 6144] = f2bf(s[t]);
    } else {
#pragma unroll
        for (int t = 0; t < 9; ++t) d[(size_t)t * 6144] = 0;
    }
}

extern "C" void kernel_launch(void* const* d_in, const int* in_sizes, int n_in,
                              void* d_out, int out_size, void* d_ws, size_t ws_size,
                              hipStream_t stream)
{
    const float* old_ = (const float*)d_in[0];
    const float* new_ = (const float*)d_in[1];
    const float* wq  = (const float*)d_in[2];  const float* bq  = (const float*)d_in[3];
    const float* wk  = (const float*)d_in[4];  const float* bk  = (const float*)d_in[5];
    const float* wv  = (const float*)d_in[6];  const float* bv  = (const float*)d_in[7];
    const float* wo1 = (const float*)d_in[8];  const float* bo1 = (const float*)d_in[9];
    const float* rw1 = (const float*)d_in[10]; const float* rw2 = (const float*)d_in[11];
    const float* wo2 = (const float*)d_in[12]; const float* bo2 = (const float*)d_in[13];
    float* out = (float*)d_out;

    char* ws = (char*)d_ws;
    // B: qh -> xvb -> h1b (32 MiB) ; C: kh -> yb_a (32 MiB)
    // D: xb(32) -> att96(48) -> yb_b(32) ; yf: fp32 y master (64 MiB); weights
    unsigned short* B   = (unsigned short*)(ws);
    unsigned short* C   = (unsigned short*)(ws + 33554432ull);
    unsigned short* D   = (unsigned short*)(ws + 67108864ull);
    float*          yf  = (float*)(ws + 117440512ull);
    unsigned short* wst = (unsigned short*)(ws + 184549376ull);   // 20*36864 bf16
    unsigned short* wv96= (unsigned short*)(ws + 186023936ull);   // 9*64*96 bf16

    const dim3 cgrid(16, 16, 4), cblk(256);

    prep_wstd<<<dim3(16, 20), 256, 0, stream>>>(wq, wk, wo1, wo2, rw1, rw2, wst);
    prep_wv<<<dim3(24), 256, 0, stream>>>(wv, wv96);
    pack_x<<<dim3(256, 4), 256, 0, stream>>>(old_, new_, D);

    // q = conv(x, wq, bq) [fp16 out]; k = conv(x, wk, bk) [fp16 out]
    conv_mfma<64, 64, true, false, false, false, false, false, true, true>
        <<<cgrid, cblk, 0, stream>>>(D, wst + 0ull * 36864, bq, nullptr, nullptr, nullptr, nullptr, B);
    conv_mfma<64, 64, true, false, false, false, false, false, true, true>
        <<<cgrid, cblk, 0, stream>>>(D, wst + 1ull * 36864, bk, nullptr, nullptr, nullptr, nullptr, C);
    // att
    local_sim<<<cgrid, cblk, 0, stream>>>(B, C, D);
    // xv = x * (conv(att, wv) + bv)   [MULX fused]
    conv_mfma<96, 32, true, false, false, false, true, false, true, false>
        <<<cgrid, cblk, 0, stream>>>(D, wv96, bv, nullptr, old_, new_, nullptr, B);
    // y = conv(xv, wo1, bo1) -> yf (fp32) + yb (C)
    conv_mfma<64, 64, true, false, false, false, false, true, true, false>
        <<<cgrid, cblk, 0, stream>>>(B, wst + 2ull * 36864, bo1, nullptr, nullptr, nullptr, yf, C);
    // 8 ResBlocks, yb ping-pong C <-> D, h1 in B
    for (int i = 0; i < 8; ++i) {
        unsigned short* src = (i & 1) ? D : C;
        unsigned short* dst = (i & 1) ? C : D;
        conv_mfma<64, 64, false, true, false, false, false, false, true, false>
            <<<cgrid, cblk, 0, stream>>>(src, wst + (size_t)(4 + i) * 36864, nullptr,
                                         nullptr, nullptr, nullptr, nullptr, B);
        conv_mfma<64, 64, false, false, true, false, false, true, true, false>
            <<<cgrid, cblk, 0, stream>>>(B, wst + (size_t)(12 + i) * 36864, nullptr,
                                         yf, nullptr, nullptr, yf, dst);
    }
    // out = conv(y, wo2, bo2) + x   [ADDX fused]; final yb is in C
    conv_mfma<64, 64, true, false, false, true, false, true, false, false>
        <<<cgrid, cblk, 0, stream>>>(C, wst + 3ull * 36864, bo2, nullptr, old_, new_, out, nullptr);
}

// Round 4
// 1257.679 us; speedup vs baseline: 1.5264x; 1.5264x over previous
//
#include <hip/hip_runtime.h>
#include <hip/hip_bf16.h>

// SRPBlock forward, MFMA bf16 implicit-GEMM convs + LDS-tiled fp16 local attention.
// x=concat(old,new) [4,64,256,256] fp32 NCHW (inputs); activations flow as
// bf16 [b][pix][ch] (channel-contiguous) for MFMA; q/k as fp16 [b][pix][64];
// y-residual master in fp32.

#define HH 256
#define WW 256
#define PLANE 65536

typedef __bf16 bf16x8 __attribute__((ext_vector_type(8)));
typedef float  f32x4  __attribute__((ext_vector_type(4)));
typedef _Float16 h2 __attribute__((ext_vector_type(2)));

__device__ __forceinline__ unsigned short f2bf(float f) {
    unsigned int u = __builtin_bit_cast(unsigned int, f);
    u += 0x7fffu + ((u >> 16) & 1u);          // RNE (finite values only)
    return (unsigned short)(u >> 16);
}

__device__ __forceinline__ unsigned short f2h(float f) {
    _Float16 h = (_Float16)f;                  // v_cvt_f16_f32 (RNE)
    return __builtin_bit_cast(unsigned short, h);
}

__device__ __forceinline__ unsigned pack2(float a, float b) {
    return (unsigned)f2bf(a) | ((unsigned)f2bf(b) << 16);
}

__device__ __forceinline__ float dot2h(unsigned a, unsigned b, float c) {
#if __has_builtin(__builtin_amdgcn_fdot2)
    return __builtin_amdgcn_fdot2(__builtin_bit_cast(h2, a),
                                  __builtin_bit_cast(h2, b), c, false);
#else
    h2 av = __builtin_bit_cast(h2, a), bv = __builtin_bit_cast(h2, b);
    return fmaf((float)av.x, (float)bv.x, fmaf((float)av.y, (float)bv.y, c));
#endif
}

// ---------------- conv3x3 (pad=1, Cout=64) via MFMA 16x16x32 bf16 ----------------
// block = 256 thr = 4 waves; tile = 16x16 pixels x 64 outch.
template <int CIN, int CH, bool BIAS, bool LEAKY, bool ADDF, bool ADDX, bool MULX,
          bool OUTF, bool OUTB, bool HALF>
__global__ __launch_bounds__(256, 2) void conv_mfma(
    const unsigned short* __restrict__ in_pc,  // [b][65536][CIN] bf16
    const unsigned short* __restrict__ wb,     // [9][64][CIN] bf16
    const float* __restrict__ bias,
    const float* __restrict__ addf,            // fp32 NCHW addend (residual)
    const float* __restrict__ xold,            // fp32 NCHW [4,32,...]
    const float* __restrict__ xnew,
    float* __restrict__ outf,                  // fp32 NCHW
    unsigned short* __restrict__ outb)         // [b][65536][64] bf16 or fp16
{
    constexpr int PARTS = CH / 8;        // 16B units per pixel-row chunk
    constexpr int SWZ   = PARTS - 1;     // XOR swizzle mask
    constexpr int KC    = CH / 32;
    constexpr int INSZ  = (324 * CH > 256 * 64) ? 324 * CH : 256 * 64;

    __shared__ unsigned short lds_in[INSZ];
    __shared__ unsigned short lds_w[2][64 * CH];

    const int tid = threadIdx.x;
    const int w   = tid >> 6;
    const int ln  = tid & 63;
    const int m   = ln & 15;    // outch-in-group for A; pixel-col for B/D
    const int q   = ln >> 4;    // quad
    const int b   = blockIdx.z;
    const int tx0 = blockIdx.x * 16, ty0 = blockIdx.y * 16;
    const size_t pixb = (size_t)b * PLANE;

    f32x4 acc[4][4];
#pragma unroll
    for (int g = 0; g < 4; ++g)
#pragma unroll
        for (int p = 0; p < 4; ++p) acc[g][p] = (f32x4)0.f;

    for (int c2 = 0; c2 < CIN / CH; ++c2) {
        // ---- stage halo chunk: 324 px x CH ch ----
        for (int u = tid; u < 324 * PARTS; u += 256) {
            int pix  = u / PARTS;
            int part = u - pix * PARTS;
            int hy = pix / 18, hx = pix - hy * 18;
            int gy = ty0 + hy - 1, gx = tx0 + hx - 1;
            uint4 val = make_uint4(0u, 0u, 0u, 0u);
            if ((unsigned)gy < 256u && (unsigned)gx < 256u)
                val = *reinterpret_cast<const uint4*>(
                    in_pc + ((pixb + (size_t)gy * 256 + gx) * CIN + c2 * CH + part * 8));
            int pp = part ^ (pix & SWZ);
            *reinterpret_cast<uint4*>(&lds_in[pix * CH + pp * 8]) = val;
        }
        // ---- stage weights tap 0 ----
        for (int u = tid; u < 64 * PARTS; u += 256) {
            int oc = u / PARTS, part = u - oc * PARTS;
            uint4 val = *reinterpret_cast<const uint4*>(
                wb + ((size_t)oc * CIN + c2 * CH + part * 8));
            int pp = part ^ (oc & SWZ);
            *reinterpret_cast<uint4*>(&lds_w[0][oc * CH + pp * 8]) = val;
        }
        __syncthreads();

        for (int t = 0; t < 9; ++t) {
            if (t < 8) {  // prefetch next tap's weights into other buffer
                int bsel = (t + 1) & 1;
                for (int u = tid; u < 64 * PARTS; u += 256) {
                    int oc = u / PARTS, part = u - oc * PARTS;
                    uint4 val = *reinterpret_cast<const uint4*>(
                        wb + ((size_t)((t + 1) * 64 + oc) * CIN + c2 * CH + part * 8));
                    int pp = part ^ (oc & SWZ);
                    *reinterpret_cast<uint4*>(&lds_w[bsel][oc * CH + pp * 8]) = val;
                }
            }
            const int dy = t / 3, dx = t - dy * 3;
            const unsigned short* wl = lds_w[t & 1];
#pragma unroll
            for (int kc = 0; kc < KC; ++kc) {
                bf16x8 av[4], bv[4];
#pragma unroll
                for (int g = 0; g < 4; ++g) {
                    int oc = g * 16 + m;
                    int pp = (kc * 4 + q) ^ (oc & SWZ);
                    av[g] = *reinterpret_cast<const bf16x8*>(&wl[oc * CH + pp * 8]);
                }
#pragma unroll
                for (int p = 0; p < 4; ++p) {
                    int hp = (w * 4 + p + dy) * 18 + m + dx;
                    int pp = (kc * 4 + q) ^ (hp & SWZ);
                    bv[p] = *reinterpret_cast<const bf16x8*>(&lds_in[hp * CH + pp * 8]);
                }
#pragma unroll
                for (int g = 0; g < 4; ++g)
#pragma unroll
                    for (int p = 0; p < 4; ++p)
                        acc[g][p] = __builtin_amdgcn_mfma_f32_16x16x32_bf16(
                            av[g], bv[p], acc[g][p], 0, 0, 0);
            }
            __syncthreads();
        }
    }

    // ---------------- epilogue ----------------
    const int colx = tx0 + m;
    float4 bvec[4];
    if (BIAS) {
#pragma unroll
        for (int g = 0; g < 4; ++g)
            bvec[g] = *reinterpret_cast<const float4*>(bias + g * 16 + q * 4);
    }

#pragma unroll
    for (int g = 0; g < 4; ++g) {
#pragma unroll
        for (int p = 0; p < 4; ++p) {
            const int prow = w * 4 + p;
            const int gy   = ty0 + prow;
            float vals[4];
#pragma unroll
            for (int r = 0; r < 4; ++r) {
                int oc = g * 16 + q * 4 + r;
                float v = acc[g][p][r];
                if (BIAS) v += reinterpret_cast<const float*>(&bvec[g])[r];
                if (LEAKY) v = (v >= 0.f) ? v : 0.2f * v;
                size_t nchw = ((size_t)(b * 64 + oc)) * PLANE + (size_t)gy * 256 + colx;
                if (ADDF) v += addf[nchw];
                if (ADDX) {
                    const float* xp = (g < 2) ? xold : xnew;
                    v += xp[((size_t)(b * 32 + (oc & 31))) * PLANE + (size_t)gy * 256 + colx];
                }
                if (MULX) {
                    const float* xp = (g < 2) ? xold : xnew;
                    v *= xp[((size_t)(b * 32 + (oc & 31))) * PLANE + (size_t)gy * 256 + colx];
                }
                if (OUTF) outf[nchw] = v;
                vals[r] = v;
            }
            if (OUTB) {  // stage to LDS for [pix][ch] vector store
                ushort4 pk;
                if (HALF) {
                    pk.x = f2h(vals[0]); pk.y = f2h(vals[1]);
                    pk.z = f2h(vals[2]); pk.w = f2h(vals[3]);
                } else {
                    pk.x = f2bf(vals[0]); pk.y = f2bf(vals[1]);
                    pk.z = f2bf(vals[2]); pk.w = f2bf(vals[3]);
                }
                int pix   = prow * 16 + m;
                int part8 = g * 4 + q;
                int p16   = (part8 >> 1) ^ (pix & 7);
                *reinterpret_cast<ushort4*>(&lds_in[pix * 64 + p16 * 8 + (part8 & 1) * 4]) = pk;
            }
        }
    }
    if (OUTB) {
        __syncthreads();
        for (int u = tid; u < 2048; u += 256) {
            int pix = u >> 3, p16 = u & 7;
            uint4 val = *reinterpret_cast<const uint4*>(
                &lds_in[pix * 64 + ((p16 ^ (pix & 7)) * 8)]);
            int gy = ty0 + (pix >> 4), gx = tx0 + (pix & 15);
            *reinterpret_cast<uint4*>(
                &outb[(pixb + (size_t)gy * 256 + gx) * 64 + p16 * 8]) = val;
        }
    }
}

// ---------------- local similarity (LDS-tiled, fp16 dot2, di-grouped) ----------------
// att[b][pix][p] = dot64(q[pix], k[pix+(di-4,dj-4)]), p=di*9+dj; ch 81..95 = 0.
// block = 256 thr = 16x16 pixel tile; k halo 24x24 staged per 32-ch chunk.
// 3 di-groups of 3 rows each -> only 27 live accumulators (no spills).
__global__ __launch_bounds__(256)
__attribute__((amdgpu_waves_per_eu(2, 4)))
void local_sim(
    const unsigned short* __restrict__ qh, const unsigned short* __restrict__ kh,
    unsigned short* __restrict__ att)
{
    __shared__ unsigned short lds_k[576 * 32];   // 24*24 px x 32ch fp16 = 36.9 KB

    const int tid = threadIdx.x;
    const int tx = tid & 15, ty = tid >> 4;
    const int bx = blockIdx.x * 16, by = blockIdx.y * 16;
    const int b  = blockIdx.z;
    const size_t pixb = (size_t)b * PLANE;

    unsigned short* op = att + (pixb + (size_t)(by + ty) * 256 + bx + tx) * 96;
    const unsigned short* qbase = qh + (pixb + (size_t)(by + ty) * 256 + bx + tx) * 64;

#pragma unroll
    for (int g = 0; g < 3; ++g) {
        float acc[27];
#pragma unroll
        for (int i = 0; i < 27; ++i) acc[i] = 0.f;

        for (int c = 0; c < 2; ++c) {
            __syncthreads();
            // stage k halo chunk: 576 px x 32 ch (zero-filled OOB)
            for (int u = tid; u < 2304; u += 256) {
                int pix = u >> 2, part = u & 3;
                int hy = pix / 24, hx = pix - hy * 24;
                int gy = by + hy - 4, gx = bx + hx - 4;
                uint4 val = make_uint4(0u, 0u, 0u, 0u);
                if ((unsigned)gy < 256u && (unsigned)gx < 256u)
                    val = *reinterpret_cast<const uint4*>(
                        kh + ((pixb + (size_t)gy * 256 + gx) * 64 + c * 32 + part * 8));
                int pp = part ^ (pix & 3) ^ ((pix >> 2) & 3);
                *reinterpret_cast<uint4*>(&lds_k[pix * 32 + pp * 8]) = val;
            }
            __syncthreads();

            uint4 qv[4];
#pragma unroll
            for (int j = 0; j < 4; ++j)
                qv[j] = *reinterpret_cast<const uint4*>(qbase + c * 32 + j * 8);

#pragma unroll
            for (int dil = 0; dil < 3; ++dil) {
                const int hrow = (ty + g * 3 + dil) * 24 + tx;
#pragma unroll
                for (int dj = 0; dj < 9; ++dj) {
                    const int hp  = hrow + dj;
                    const int fsw = (hp & 3) ^ ((hp >> 2) & 3);
                    float s = acc[dil * 9 + dj];
#pragma unroll
                    for (int part = 0; part < 4; ++part) {
                        const uint4 kv = *reinterpret_cast<const uint4*>(
                            &lds_k[hp * 32 + ((part ^ fsw) * 8)]);
                        s = dot2h(qv[part].x, kv.x, s);
                        s = dot2h(qv[part].y, kv.y, s);
                        s = dot2h(qv[part].z, kv.z, s);
                        s = dot2h(qv[part].w, kv.w, s);
                    }
                    acc[dil * 9 + dj] = s;
                }
            }
        }

        // ---- store this group's 27 bf16 values at op + g*27 (byte base 54*g) ----
        unsigned short* o = op + g * 27;
        if (g == 0) {            // byte 0: 16|16|8|8|4|2
            uint4 A = {pack2(acc[0], acc[1]),  pack2(acc[2], acc[3]),
                       pack2(acc[4], acc[5]),  pack2(acc[6], acc[7])};
            uint4 B = {pack2(acc[8], acc[9]),  pack2(acc[10], acc[11]),
                       pack2(acc[12], acc[13]), pack2(acc[14], acc[15])};
            uint2 C = {pack2(acc[16], acc[17]), pack2(acc[18], acc[19])};
            uint2 D = {pack2(acc[20], acc[21]), pack2(acc[22], acc[23])};
            *reinterpret_cast<uint4*>(o)      = A;
            *reinterpret_cast<uint4*>(o + 8)  = B;
            *reinterpret_cast<uint2*>(o + 16) = C;
            *reinterpret_cast<uint2*>(o + 20) = D;
            *reinterpret_cast<unsigned*>(o + 24) = pack2(acc[24], acc[25]);
            o[26] = f2bf(acc[26]);
        } else if (g == 1) {     // byte 54: 2|4|4|16|16|8|4
            o[0] = f2bf(acc[0]);
            *reinterpret_cast<unsigned*>(o + 1) = pack2(acc[1], acc[2]);
            *reinterpret_cast<unsigned*>(o + 3) = pack2(acc[3], acc[4]);
            uint4 A = {pack2(acc[5], acc[6]),   pack2(acc[7], acc[8]),
                       pack2(acc[9], acc[10]),  pack2(acc[11], acc[12])};
            uint4 B = {pack2(acc[13], acc[14]), pack2(acc[15], acc[16]),
                       pack2(acc[17], acc[18]), pack2(acc[19], acc[20])};
            *reinterpret_cast<uint4*>(o + 5)  = A;
            *reinterpret_cast<uint4*>(o + 13) = B;
            uint2 C = {pack2(acc[21], acc[22]), pack2(acc[23], acc[24])};
            *reinterpret_cast<uint2*>(o + 21) = C;
            *reinterpret_cast<unsigned*>(o + 25) = pack2(acc[25], acc[26]);
        } else {                 // byte 108: 4|16|16|8|4|4|2
            *reinterpret_cast<unsigned*>(o) = pack2(acc[0], acc[1]);
            uint4 A = {pack2(acc[2], acc[3]),   pack2(acc[4], acc[5]),
                       pack2(acc[6], acc[7]),   pack2(acc[8], acc[9])};
            uint4 B = {pack2(acc[10], acc[11]), pack2(acc[12], acc[13]),
                       pack2(acc[14], acc[15]), pack2(acc[16], acc[17])};
            *reinterpret_cast<uint4*>(o + 2)  = A;
            *reinterpret_cast<uint4*>(o + 10) = B;
            uint2 C = {pack2(acc[18], acc[19]), pack2(acc[20], acc[21])};
            *reinterpret_cast<uint2*>(o + 18) = C;
            *reinterpret_cast<unsigned*>(o + 22) = pack2(acc[22], acc[23]);
            *reinterpret_cast<unsigned*>(o + 24) = pack2(acc[24], acc[25]);
            o[26] = f2bf(acc[26]);
        }
    }

    // zero channels 81..95
    op[81] = 0;
    *reinterpret_cast<unsigned*>(op + 82) = 0u;
    uint2 z2 = {0u, 0u};
    uint4 z4 = {0u, 0u, 0u, 0u};
    *reinterpret_cast<uint2*>(op + 84) = z2;
    *reinterpret_cast<uint4*>(op + 88) = z4;
}

// ---------------- pack x: fp32 NCHW old/new -> bf16 [b][pix][64] ----------------
__global__ __launch_bounds__(256) void pack_x(
    const float* __restrict__ old_, const float* __restrict__ new_,
    unsigned short* __restrict__ xb)
{
    __shared__ unsigned short lds[256 * 64];
    const int tid = threadIdx.x;
    const int b = blockIdx.y;
    const size_t pixbase = (size_t)blockIdx.x * 256;
#pragma unroll
    for (int cg = 0; cg < 8; ++cg) {
        unsigned pk[4];
#pragma unroll
        for (int h = 0; h < 4; ++h) {
            int c0 = cg * 8 + h * 2;
            const float* s0 = (c0 < 32) ? old_ : new_;
            const float* s1 = ((c0 + 1) < 32) ? old_ : new_;
            float f0 = s0[((size_t)b * 32 + (c0 & 31)) * PLANE + pixbase + tid];
            float f1 = s1[((size_t)b * 32 + ((c0 + 1) & 31)) * PLANE + pixbase + tid];
            pk[h] = f2bf(f0) | ((unsigned)f2bf(f1) << 16);
        }
        int p16 = cg ^ (tid & 7);
        uint4 v; v.x = pk[0]; v.y = pk[1]; v.z = pk[2]; v.w = pk[3];
        *reinterpret_cast<uint4*>(&lds[tid * 64 + p16 * 8]) = v;
    }
    __syncthreads();
    for (int r = 0; r < 8; ++r) {
        int u = r * 256 + tid;
        int pix = u >> 3, p16 = u & 7;
        uint4 v = *reinterpret_cast<const uint4*>(&lds[pix * 64 + ((p16 ^ (pix & 7)) * 8)]);
        *reinterpret_cast<uint4*>(
            &xb[((size_t)b * PLANE + pixbase + pix) * 64 + p16 * 8]) = v;
    }
}

// ---------------- weight prep: fp32 OIHW -> bf16 [9][64][CIN] ----------------
__global__ void prep_wstd(const float* __restrict__ wq, const float* __restrict__ wk,
                          const float* __restrict__ wo1, const float* __restrict__ wo2,
                          const float* __restrict__ rw1, const float* __restrict__ rw2,
                          unsigned short* __restrict__ wstd)
{
    const int c = blockIdx.y;  // 0..19
    const float* src;
    if (c == 0) src = wq;
    else if (c == 1) src = wk;
    else if (c == 2) src = wo1;
    else if (c == 3) src = wo2;
    else if (c < 12) src = rw1 + (size_t)(c - 4) * 36864;
    else src = rw2 + (size_t)(c - 12) * 36864;
    int idx = blockIdx.x * 256 + threadIdx.x;  // 0..4095
    int o = idx >> 6, i = idx & 63;
    const float* s = src + (size_t)(o * 64 + i) * 9;
    unsigned short* d = wstd + (size_t)c * 36864 + (size_t)o * 64 + i;
#pragma unroll
    for (int t = 0; t < 9; ++t) d[(size_t)t * 4096] = f2bf(s[t]);
}

__global__ void prep_wv(const float* __restrict__ wv, unsigned short* __restrict__ wv96)
{
    int idx = blockIdx.x * 256 + threadIdx.x;  // < 6144
    int o = idx / 96, i = idx - o * 96;
    unsigned short* d = wv96 + (size_t)o * 96 + i;
    if (i < 81) {
        const float* s = wv + (size_t)(o * 81 + i) * 9;
#pragma unroll
        for (int t = 0; t < 9; ++t) d[(size_t)t * 6144] = f2bf(s[t]);
    } else {
#pragma unroll
        for (int t = 0; t < 9; ++t) d[(size_t)t * 6144] = 0;
    }
}

extern "C" void kernel_launch(void* const* d_in, const int* in_sizes, int n_in,
                              void* d_out, int out_size, void* d_ws, size_t ws_size,
                              hipStream_t stream)
{
    const float* old_ = (const float*)d_in[0];
    const float* new_ = (const float*)d_in[1];
    const float* wq  = (const float*)d_in[2];  const float* bq  = (const float*)d_in[3];
    const float* wk  = (const float*)d_in[4];  const float* bk  = (const float*)d_in[5];
    const float* wv  = (const float*)d_in[6];  const float* bv  = (const float*)d_in[7];
    const float* wo1 = (const float*)d_in[8];  const float* bo1 = (const float*)d_in[9];
    const float* rw1 = (const float*)d_in[10]; const float* rw2 = (const float*)d_in[11];
    const float* wo2 = (const float*)d_in[12]; const float* bo2 = (const float*)d_in[13];
    float* out = (float*)d_out;

    char* ws = (char*)d_ws;
    // B: qh -> xvb -> h1b (32 MiB) ; C: kh -> yb_a (32 MiB)
    // D: xb(32) -> att96(48) -> yb_b(32) ; yf: fp32 y master (64 MiB); weights
    unsigned short* B   = (unsigned short*)(ws);
    unsigned short* C   = (unsigned short*)(ws + 33554432ull);
    unsigned short* D   = (unsigned short*)(ws + 67108864ull);
    float*          yf  = (float*)(ws + 117440512ull);
    unsigned short* wst = (unsigned short*)(ws + 184549376ull);   // 20*36864 bf16
    unsigned short* wv96= (unsigned short*)(ws + 186023936ull);   // 9*64*96 bf16

    const dim3 cgrid(16, 16, 4), cblk(256);

    prep_wstd<<<dim3(16, 20), 256, 0, stream>>>(wq, wk, wo1, wo2, rw1, rw2, wst);
    prep_wv<<<dim3(24), 256, 0, stream>>>(wv, wv96);
    pack_x<<<dim3(256, 4), 256, 0, stream>>>(old_, new_, D);

    // q = conv(x, wq, bq) [fp16 out]; k = conv(x, wk, bk) [fp16 out]
    conv_mfma<64, 64, true, false, false, false, false, false, true, true>
        <<<cgrid, cblk, 0, stream>>>(D, wst + 0ull * 36864, bq, nullptr, nullptr, nullptr, nullptr, B);
    conv_mfma<64, 64, true, false, false, false, false, false, true, true>
        <<<cgrid, cblk, 0, stream>>>(D, wst + 1ull * 36864, bk, nullptr, nullptr, nullptr, nullptr, C);
    // att
    local_sim<<<cgrid, cblk, 0, stream>>>(B, C, D);
    // xv = x * (conv(att, wv) + bv)   [MULX fused]
    conv_mfma<96, 32, true, false, false, false, true, false, true, false>
        <<<cgrid, cblk, 0, stream>>>(D, wv96, bv, nullptr, old_, new_, nullptr, B);
    // y = conv(xv, wo1, bo1) -> yf (fp32) + yb (C)
    conv_mfma<64, 64, true, false, false, false, false, true, true, false>
        <<<cgrid, cblk, 0, stream>>>(B, wst + 2ull * 36864, bo1, nullptr, nullptr, nullptr, yf, C);
    // 8 ResBlocks, yb ping-pong C <-> D, h1 in B
    for (int i = 0; i < 8; ++i) {
        unsigned short* src = (i & 1) ? D : C;
        unsigned short* dst = (i & 1) ? C : D;
        conv_mfma<64, 64, false, true, false, false, false, false, true, false>
            <<<cgrid, cblk, 0, stream>>>(src, wst + (size_t)(4 + i) * 36864, nullptr,
                                         nullptr, nullptr, nullptr, nullptr, B);
        conv_mfma<64, 64, false, false, true, false, false, true, true, false>
            <<<cgrid, cblk, 0, stream>>>(B, wst + (size_t)(12 + i) * 36864, nullptr,
                                         yf, nullptr, nullptr, yf, dst);
    }
    // out = conv(y, wo2, bo2) + x   [ADDX fused]; final yb is in C
    conv_mfma<64, 64, true, false, false, true, false, true, false, false>
        <<<cgrid, cblk, 0, stream>>>(C, wst + 3ull * 36864, bo2, nullptr, old_, new_, out, nullptr);
}

// Round 5
// 889.596 us; speedup vs baseline: 2.1580x; 1.4138x over previous
//
#include <hip/hip_runtime.h>
#include <hip/hip_bf16.h>

// SRPBlock forward — fp16 end-to-end MFMA implicit-GEMM convs + LDS-tiled local attention.
// x=concat(old,new) [4,64,256,256] fp32 NCHW inputs; all activations flow as fp16
// [b][pix][ch] (channel-contiguous); fp32 accumulate everywhere; final out fp32 NCHW.

#define HH 256
#define WW 256
#define PLANE 65536

typedef _Float16 f16x8 __attribute__((ext_vector_type(8)));
typedef float    f32x4 __attribute__((ext_vector_type(4)));
typedef _Float16 h2    __attribute__((ext_vector_type(2)));

__device__ __forceinline__ unsigned short f2h(float f) {
    _Float16 h = (_Float16)f;                  // v_cvt_f16_f32 (RNE)
    return __builtin_bit_cast(unsigned short, h);
}
__device__ __forceinline__ float h2f(unsigned short u) {
    return (float)__builtin_bit_cast(_Float16, u);
}
__device__ __forceinline__ unsigned pack2h(float a, float b) {
    return (unsigned)f2h(a) | ((unsigned)f2h(b) << 16);
}
__device__ __forceinline__ float dot2h(unsigned a, unsigned b, float c) {
#if __has_builtin(__builtin_amdgcn_fdot2)
    return __builtin_amdgcn_fdot2(__builtin_bit_cast(h2, a),
                                  __builtin_bit_cast(h2, b), c, false);
#else
    h2 av = __builtin_bit_cast(h2, a), bv = __builtin_bit_cast(h2, b);
    return fmaf((float)av.x, (float)bv.x, fmaf((float)av.y, (float)bv.y, c));
#endif
}

// ---------------- conv3x3 (pad=1, Cout=64) via MFMA 16x16x32 f16 ----------------
// block = 256 thr = 4 waves; tile = 16x16 pixels x 64 outch.
// K = 9 taps x CIN, chunked by 32 channels; ALL 9 taps' weights staged per chunk
// -> only 2 barriers per chunk, 144 straight-line MFMAs between barriers.
// LDS: in 324px*32ch (20.25KB) + w 9*64*32 (36KB) = 57.6KB, union'd with the
// 32KB epilogue transpose region.
template <int CIN, bool BIAS, bool LEAKY, bool ADDF, bool ADDX, bool MULX, bool OUTF, bool OUTB>
__global__ __launch_bounds__(256, 2) void conv_mfma(
    const unsigned short* __restrict__ in_pc,  // [b][65536][CIN] fp16
    const unsigned short* __restrict__ wb,     // [9][64][CIN] fp16
    const float* __restrict__ bias,
    const unsigned short* __restrict__ addh,   // fp16 [b][pix][64] addend (residual)
    const unsigned short* __restrict__ xh,     // fp16 [b][pix][64] (concat x)
    float* __restrict__ outf,                  // fp32 NCHW
    unsigned short* __restrict__ outb)         // fp16 [b][65536][64]
{
    __shared__ unsigned short smem[28800];     // 57.6 KB
    unsigned short* lds_in = smem;             // 324*32 = 10368 halves
    unsigned short* lds_w  = smem + 10368;     // 9*64*32 = 18432 halves

    const int tid = threadIdx.x;
    const int w   = tid >> 6;
    const int ln  = tid & 63;
    const int m   = ln & 15;    // outch-in-group for A; pixel-col for B/D
    const int q   = ln >> 4;    // quad
    const int b   = blockIdx.z;
    const int tx0 = blockIdx.x * 16, ty0 = blockIdx.y * 16;
    const size_t pixb = (size_t)b * PLANE;

    f32x4 acc[4][4];
#pragma unroll
    for (int g = 0; g < 4; ++g)
#pragma unroll
        for (int p = 0; p < 4; ++p) acc[g][p] = (f32x4)0.f;

    for (int c2 = 0; c2 < CIN / 32; ++c2) {
        __syncthreads();   // protect previous chunk's reads / epilogue region
        // ---- stage input halo chunk: 324 px x 32 ch (zero-filled OOB) ----
        for (int u = tid; u < 1296; u += 256) {
            int pix = u >> 2, part = u & 3;
            int hy = pix / 18, hx = pix - hy * 18;
            int gy = ty0 + hy - 1, gx = tx0 + hx - 1;
            uint4 val = make_uint4(0u, 0u, 0u, 0u);
            if ((unsigned)gy < 256u && (unsigned)gx < 256u)
                val = *reinterpret_cast<const uint4*>(
                    in_pc + ((pixb + (size_t)gy * 256 + gx) * CIN + c2 * 32 + part * 8));
            *reinterpret_cast<uint4*>(&lds_in[pix * 32 + ((part ^ (pix & 3)) * 8)]) = val;
        }
        // ---- stage ALL 9 taps' weights for this chunk: 9 x 64 oc x 32 ch ----
#pragma unroll
        for (int t = 0; t < 9; ++t) {
            int oc = tid >> 2, part = tid & 3;
            uint4 val = *reinterpret_cast<const uint4*>(
                wb + ((size_t)(t * 64 + oc) * CIN + c2 * 32 + part * 8));
            *reinterpret_cast<uint4*>(
                &lds_w[t * 2048 + oc * 32 + ((part ^ (oc & 3)) * 8)]) = val;
        }
        __syncthreads();

#pragma unroll
        for (int t = 0; t < 9; ++t) {
            const int dy = t / 3, dx = t - dy * 3;
            f16x8 av[4], bv[4];
#pragma unroll
            for (int g = 0; g < 4; ++g) {
                int oc = g * 16 + m;
                av[g] = *reinterpret_cast<const f16x8*>(
                    &lds_w[t * 2048 + oc * 32 + ((q ^ (oc & 3)) * 8)]);
            }
#pragma unroll
            for (int p = 0; p < 4; ++p) {
                int hp = (w * 4 + p + dy) * 18 + m + dx;
                bv[p] = *reinterpret_cast<const f16x8*>(
                    &lds_in[hp * 32 + ((q ^ (hp & 3)) * 8)]);
            }
#pragma unroll
            for (int g = 0; g < 4; ++g)
#pragma unroll
                for (int p = 0; p < 4; ++p)
                    acc[g][p] = __builtin_amdgcn_mfma_f32_16x16x32_f16(
                        av[g], bv[p], acc[g][p], 0, 0, 0);
        }
    }

    // ---------------- epilogue ----------------
    // D layout: row(outch-in-grp) = q*4+reg, col(pixel) = m
    const int colx = tx0 + m;
    float4 bvec[4];
    if (BIAS) {
#pragma unroll
        for (int g = 0; g < 4; ++g)
            bvec[g] = *reinterpret_cast<const float4*>(bias + g * 16 + q * 4);
    }
    if (OUTB) __syncthreads();   // protect last tap's LDS reads before overwrite

#pragma unroll
    for (int g = 0; g < 4; ++g) {
#pragma unroll
        for (int p = 0; p < 4; ++p) {
            const int prow = w * 4 + p;
            const int gy   = ty0 + prow;
            const size_t pixg = pixb + (size_t)gy * 256 + colx;
            const int oc0 = g * 16 + q * 4;
            ushort4 a4, x4;
            if (ADDF) a4 = *reinterpret_cast<const ushort4*>(addh + pixg * 64 + oc0);
            if (ADDX || MULX) x4 = *reinterpret_cast<const ushort4*>(xh + pixg * 64 + oc0);
            float vals[4];
#pragma unroll
            for (int r = 0; r < 4; ++r) {
                float v = acc[g][p][r];
                if (BIAS) v += reinterpret_cast<const float*>(&bvec[g])[r];
                if (LEAKY) v = (v >= 0.f) ? v : 0.2f * v;
                if (ADDF) v += h2f(reinterpret_cast<const unsigned short*>(&a4)[r]);
                if (ADDX) v += h2f(reinterpret_cast<const unsigned short*>(&x4)[r]);
                if (MULX) v *= h2f(reinterpret_cast<const unsigned short*>(&x4)[r]);
                if (OUTF)
                    outf[((size_t)(b * 64 + oc0 + r)) * PLANE + (size_t)gy * 256 + colx] = v;
                vals[r] = v;
            }
            if (OUTB) {  // stage to LDS for [pix][64] vector store
                ushort4 pk;
                pk.x = f2h(vals[0]); pk.y = f2h(vals[1]);
                pk.z = f2h(vals[2]); pk.w = f2h(vals[3]);
                int pix   = prow * 16 + m;
                int part8 = g * 4 + q;
                int p16   = (part8 >> 1) ^ (pix & 7);
                *reinterpret_cast<ushort4*>(&smem[pix * 64 + p16 * 8 + (part8 & 1) * 4]) = pk;
            }
        }
    }
    if (OUTB) {
        __syncthreads();
        for (int u = tid; u < 2048; u += 256) {
            int pix = u >> 3, p16 = u & 7;
            uint4 val = *reinterpret_cast<const uint4*>(
                &smem[pix * 64 + ((p16 ^ (pix & 7)) * 8)]);
            int gy = ty0 + (pix >> 4), gx = tx0 + (pix & 15);
            *reinterpret_cast<uint4*>(
                &outb[(pixb + (size_t)gy * 256 + gx) * 64 + p16 * 8]) = val;
        }
    }
}

// ---------------- local similarity (LDS-tiled, fp16 dot2, di-grouped) ----------------
// att[b][pix][p] = dot64(q[pix], k[pix+(di-4,dj-4)]), p=di*9+dj; ch 81..95 = 0.
__global__ __launch_bounds__(256)
__attribute__((amdgpu_waves_per_eu(2, 4)))
void local_sim(
    const unsigned short* __restrict__ qh, const unsigned short* __restrict__ kh,
    unsigned short* __restrict__ att)
{
    __shared__ unsigned short lds_k[576 * 32];   // 24*24 px x 32ch fp16 = 36.9 KB

    const int tid = threadIdx.x;
    const int tx = tid & 15, ty = tid >> 4;
    const int bx = blockIdx.x * 16, by = blockIdx.y * 16;
    const int b  = blockIdx.z;
    const size_t pixb = (size_t)b * PLANE;

    unsigned short* op = att + (pixb + (size_t)(by + ty) * 256 + bx + tx) * 96;
    const unsigned short* qbase = qh + (pixb + (size_t)(by + ty) * 256 + bx + tx) * 64;

#pragma unroll
    for (int g = 0; g < 3; ++g) {
        float acc[27];
#pragma unroll
        for (int i = 0; i < 27; ++i) acc[i] = 0.f;

        for (int c = 0; c < 2; ++c) {
            __syncthreads();
            for (int u = tid; u < 2304; u += 256) {
                int pix = u >> 2, part = u & 3;
                int hy = pix / 24, hx = pix - hy * 24;
                int gy = by + hy - 4, gx = bx + hx - 4;
                uint4 val = make_uint4(0u, 0u, 0u, 0u);
                if ((unsigned)gy < 256u && (unsigned)gx < 256u)
                    val = *reinterpret_cast<const uint4*>(
                        kh + ((pixb + (size_t)gy * 256 + gx) * 64 + c * 32 + part * 8));
                int pp = part ^ (pix & 3) ^ ((pix >> 2) & 3);
                *reinterpret_cast<uint4*>(&lds_k[pix * 32 + pp * 8]) = val;
            }
            __syncthreads();

            uint4 qv[4];
#pragma unroll
            for (int j = 0; j < 4; ++j)
                qv[j] = *reinterpret_cast<const uint4*>(qbase + c * 32 + j * 8);

#pragma unroll
            for (int dil = 0; dil < 3; ++dil) {
                const int hrow = (ty + g * 3 + dil) * 24 + tx;
#pragma unroll
                for (int dj = 0; dj < 9; ++dj) {
                    const int hp  = hrow + dj;
                    const int fsw = (hp & 3) ^ ((hp >> 2) & 3);
                    float s = acc[dil * 9 + dj];
#pragma unroll
                    for (int part = 0; part < 4; ++part) {
                        const uint4 kv = *reinterpret_cast<const uint4*>(
                            &lds_k[hp * 32 + ((part ^ fsw) * 8)]);
                        s = dot2h(qv[part].x, kv.x, s);
                        s = dot2h(qv[part].y, kv.y, s);
                        s = dot2h(qv[part].z, kv.z, s);
                        s = dot2h(qv[part].w, kv.w, s);
                    }
                    acc[dil * 9 + dj] = s;
                }
            }
        }

        // ---- store this group's 27 fp16 values at op + g*27 ----
        unsigned short* o = op + g * 27;
        if (g == 0) {
            uint4 A = {pack2h(acc[0], acc[1]),  pack2h(acc[2], acc[3]),
                       pack2h(acc[4], acc[5]),  pack2h(acc[6], acc[7])};
            uint4 B = {pack2h(acc[8], acc[9]),  pack2h(acc[10], acc[11]),
                       pack2h(acc[12], acc[13]), pack2h(acc[14], acc[15])};
            uint2 C = {pack2h(acc[16], acc[17]), pack2h(acc[18], acc[19])};
            uint2 D = {pack2h(acc[20], acc[21]), pack2h(acc[22], acc[23])};
            *reinterpret_cast<uint4*>(o)      = A;
            *reinterpret_cast<uint4*>(o + 8)  = B;
            *reinterpret_cast<uint2*>(o + 16) = C;
            *reinterpret_cast<uint2*>(o + 20) = D;
            *reinterpret_cast<unsigned*>(o + 24) = pack2h(acc[24], acc[25]);
            o[26] = f2h(acc[26]);
        } else if (g == 1) {
            o[0] = f2h(acc[0]);
            *reinterpret_cast<unsigned*>(o + 1) = pack2h(acc[1], acc[2]);
            *reinterpret_cast<unsigned*>(o + 3) = pack2h(acc[3], acc[4]);
            uint4 A = {pack2h(acc[5], acc[6]),   pack2h(acc[7], acc[8]),
                       pack2h(acc[9], acc[10]),  pack2h(acc[11], acc[12])};
            uint4 B = {pack2h(acc[13], acc[14]), pack2h(acc[15], acc[16]),
                       pack2h(acc[17], acc[18]), pack2h(acc[19], acc[20])};
            *reinterpret_cast<uint4*>(o + 5)  = A;
            *reinterpret_cast<uint4*>(o + 13) = B;
            uint2 C = {pack2h(acc[21], acc[22]), pack2h(acc[23], acc[24])};
            *reinterpret_cast<uint2*>(o + 21) = C;
            *reinterpret_cast<unsigned*>(o + 25) = pack2h(acc[25], acc[26]);
        } else {
            *reinterpret_cast<unsigned*>(o) = pack2h(acc[0], acc[1]);
            uint4 A = {pack2h(acc[2], acc[3]),   pack2h(acc[4], acc[5]),
                       pack2h(acc[6], acc[7]),   pack2h(acc[8], acc[9])};
            uint4 B = {pack2h(acc[10], acc[11]), pack2h(acc[12], acc[13]),
                       pack2h(acc[14], acc[15]), pack2h(acc[16], acc[17])};
            *reinterpret_cast<uint4*>(o + 2)  = A;
            *reinterpret_cast<uint4*>(o + 10) = B;
            uint2 C = {pack2h(acc[18], acc[19]), pack2h(acc[20], acc[21])};
            *reinterpret_cast<uint2*>(o + 18) = C;
            *reinterpret_cast<unsigned*>(o + 22) = pack2h(acc[22], acc[23]);
            *reinterpret_cast<unsigned*>(o + 24) = pack2h(acc[24], acc[25]);
            o[26] = f2h(acc[26]);
        }
    }

    // zero channels 81..95
    op[81] = 0;
    *reinterpret_cast<unsigned*>(op + 82) = 0u;
    uint2 z2 = {0u, 0u};
    uint4 z4 = {0u, 0u, 0u, 0u};
    *reinterpret_cast<uint2*>(op + 84) = z2;
    *reinterpret_cast<uint4*>(op + 88) = z4;
}

// ---------------- pack x: fp32 NCHW old/new -> fp16 [b][pix][64] ----------------
__global__ __launch_bounds__(256) void pack_x(
    const float* __restrict__ old_, const float* __restrict__ new_,
    unsigned short* __restrict__ xb)
{
    __shared__ unsigned short lds[256 * 64];
    const int tid = threadIdx.x;
    const int b = blockIdx.y;
    const size_t pixbase = (size_t)blockIdx.x * 256;
#pragma unroll
    for (int cg = 0; cg < 8; ++cg) {
        unsigned pk[4];
#pragma unroll
        for (int h = 0; h < 4; ++h) {
            int c0 = cg * 8 + h * 2;
            const float* s0 = (c0 < 32) ? old_ : new_;
            const float* s1 = ((c0 + 1) < 32) ? old_ : new_;
            float f0 = s0[((size_t)b * 32 + (c0 & 31)) * PLANE + pixbase + tid];
            float f1 = s1[((size_t)b * 32 + ((c0 + 1) & 31)) * PLANE + pixbase + tid];
            pk[h] = pack2h(f0, f1);
        }
        int p16 = cg ^ (tid & 7);
        uint4 v; v.x = pk[0]; v.y = pk[1]; v.z = pk[2]; v.w = pk[3];
        *reinterpret_cast<uint4*>(&lds[tid * 64 + p16 * 8]) = v;
    }
    __syncthreads();
    for (int r = 0; r < 8; ++r) {
        int u = r * 256 + tid;
        int pix = u >> 3, p16 = u & 7;
        uint4 v = *reinterpret_cast<const uint4*>(&lds[pix * 64 + ((p16 ^ (pix & 7)) * 8)]);
        *reinterpret_cast<uint4*>(
            &xb[((size_t)b * PLANE + pixbase + pix) * 64 + p16 * 8]) = v;
    }
}

// ---------------- weight prep: fp32 OIHW -> fp16 [9][64][CIN] ----------------
__global__ void prep_wstd(const float* __restrict__ wq, const float* __restrict__ wk,
                          const float* __restrict__ wo1, const float* __restrict__ wo2,
                          const float* __restrict__ rw1, const float* __restrict__ rw2,
                          unsigned short* __restrict__ wstd)
{
    const int c = blockIdx.y;  // 0..19
    const float* src;
    if (c == 0) src = wq;
    else if (c == 1) src = wk;
    else if (c == 2) src = wo1;
    else if (c == 3) src = wo2;
    else if (c < 12) src = rw1 + (size_t)(c - 4) * 36864;
    else src = rw2 + (size_t)(c - 12) * 36864;
    int idx = blockIdx.x * 256 + threadIdx.x;  // 0..4095
    int o = idx >> 6, i = idx & 63;
    const float* s = src + (size_t)(o * 64 + i) * 9;
    unsigned short* d = wstd + (size_t)c * 36864 + (size_t)o * 64 + i;
#pragma unroll
    for (int t = 0; t < 9; ++t) d[(size_t)t * 4096] = f2h(s[t]);
}

__global__ void prep_wv(const float* __restrict__ wv, unsigned short* __restrict__ wv96)
{
    int idx = blockIdx.x * 256 + threadIdx.x;  // < 6144
    int o = idx / 96, i = idx - o * 96;
    unsigned short* d = wv96 + (size_t)o * 96 + i;
    if (i < 81) {
        const float* s = wv + (size_t)(o * 81 + i) * 9;
#pragma unroll
        for (int t = 0; t < 9; ++t) d[(size_t)t * 6144] = f2h(s[t]);
    } else {
#pragma unroll
        for (int t = 0; t < 9; ++t) d[(size_t)t * 6144] = 0;
    }
}

extern "C" void kernel_launch(void* const* d_in, const int* in_sizes, int n_in,
                              void* d_out, int out_size, void* d_ws, size_t ws_size,
                              hipStream_t stream)
{
    const float* old_ = (const float*)d_in[0];
    const float* new_ = (const float*)d_in[1];
    const float* wq  = (const float*)d_in[2];  const float* bq  = (const float*)d_in[3];
    const float* wk  = (const float*)d_in[4];  const float* bk  = (const float*)d_in[5];
    const float* wv  = (const float*)d_in[6];  const float* bv  = (const float*)d_in[7];
    const float* wo1 = (const float*)d_in[8];  const float* bo1 = (const float*)d_in[9];
    const float* rw1 = (const float*)d_in[10]; const float* rw2 = (const float*)d_in[11];
    const float* wo2 = (const float*)d_in[12]; const float* bo2 = (const float*)d_in[13];
    float* out = (float*)d_out;

    char* ws = (char*)d_ws;
    // X : xh fp16 (32 MiB, persistent)
    // P1: q -> y_a (32 MiB) ; P2: k -> xv -> h1 (32 MiB) ; P3: att96(48) -> y_b
    unsigned short* X   = (unsigned short*)(ws);
    unsigned short* P1  = (unsigned short*)(ws + 33554432ull);
    unsigned short* P2  = (unsigned short*)(ws + 67108864ull);
    unsigned short* P3  = (unsigned short*)(ws + 100663296ull);
    unsigned short* wst = (unsigned short*)(ws + 150994944ull);   // 20*36864 fp16
    unsigned short* wv96= (unsigned short*)(ws + 152469504ull);   // 9*64*96 fp16

    const dim3 cgrid(16, 16, 4), cblk(256);

    prep_wstd<<<dim3(16, 20), 256, 0, stream>>>(wq, wk, wo1, wo2, rw1, rw2, wst);
    prep_wv<<<dim3(24), 256, 0, stream>>>(wv, wv96);
    pack_x<<<dim3(256, 4), 256, 0, stream>>>(old_, new_, X);

    // q = conv(x, wq, bq); k = conv(x, wk, bk)
    conv_mfma<64, true, false, false, false, false, false, true>
        <<<cgrid, cblk, 0, stream>>>(X, wst + 0ull * 36864, bq, nullptr, nullptr, nullptr, P1);
    conv_mfma<64, true, false, false, false, false, false, true>
        <<<cgrid, cblk, 0, stream>>>(X, wst + 1ull * 36864, bk, nullptr, nullptr, nullptr, P2);
    // att (fp16, 96ch padded)
    local_sim<<<cgrid, cblk, 0, stream>>>(P1, P2, P3);
    // xv = x * (conv(att, wv) + bv)   [MULX fused]
    conv_mfma<96, true, false, false, false, true, false, true>
        <<<cgrid, cblk, 0, stream>>>(P3, wv96, bv, nullptr, X, nullptr, P2);
    // y0 = conv(xv, wo1, bo1) -> P1
    conv_mfma<64, true, false, false, false, false, false, true>
        <<<cgrid, cblk, 0, stream>>>(P2, wst + 2ull * 36864, bo1, nullptr, nullptr, nullptr, P1);
    // 8 ResBlocks; y ping-pong P1 <-> P3, h1 in P2; residual add fused in conv2
    for (int i = 0; i < 8; ++i) {
        unsigned short* ysrc = (i & 1) ? P3 : P1;
        unsigned short* ydst = (i & 1) ? P1 : P3;
        conv_mfma<64, false, true, false, false, false, false, true>
            <<<cgrid, cblk, 0, stream>>>(ysrc, wst + (size_t)(4 + i) * 36864, nullptr,
                                         nullptr, nullptr, nullptr, P2);
        conv_mfma<64, false, false, true, false, false, false, true>
            <<<cgrid, cblk, 0, stream>>>(P2, wst + (size_t)(12 + i) * 36864, nullptr,
                                         ysrc, nullptr, nullptr, ydst);
    }
    // out = conv(y, wo2, bo2) + x   [ADDX fused]; final y in P1
    conv_mfma<64, true, false, false, true, false, true, false>
        <<<cgrid, cblk, 0, stream>>>(P1, wst + 3ull * 36864, bo2, nullptr, X, out, nullptr);
}